// Round 9
// baseline (225.283 us; speedup 1.0000x reference)
//
#include <hip/hip_runtime.h>
#include <stdint.h>

#define Nn 4
#define Cc 64
#define LL 4096   // H*W
#define KK 256    // feature dim: 64 channels * 4 causal taps
#define TRI2 528  // 32*33/2 triangular 128x128 tile pairs per batch

typedef _Float16 half8 __attribute__((ext_vector_type(8)));
typedef float f32x16 __attribute__((ext_vector_type(16)));
typedef float f4a __attribute__((ext_vector_type(4), aligned(4)));

__device__ __forceinline__ unsigned f2ord(float f) {
    unsigned u = __float_as_uint(f);
    return u ^ ((u & 0x80000000u) ? 0xFFFFFFFFu : 0x80000000u);
}
__device__ __forceinline__ float ord2f(unsigned o) {
    unsigned u = (o & 0x80000000u) ? (o ^ 0x80000000u) : ~o;
    return __uint_as_float(u);
}
__device__ __forceinline__ unsigned short h2u(_Float16 h) {
    union { _Float16 f; unsigned short u; } x; x.f = h; return x.u;
}

// Kernel 1: normalized masked context vectors, split fp16 hi/lo, both pre-scaled:
//   Vh' = 2048*fp16(v)  (exact pow2),  Vl = fp16((v - fp16(v)) * 2048)
// Layout: [n][l][k], k = c*4+tap contiguous. 16 lanes cooperate per l (4 ch each).
// XCD-pinned and zeroes its slice of `best` (replaces memset dispatch).
__global__ __launch_bounds__(256) void build_v(const float* __restrict__ yhat,
                                               unsigned short* __restrict__ VhT,
                                               unsigned short* __restrict__ VlT,
                                               unsigned long long* __restrict__ best) {
    int blk = blockIdx.x;                       // 0..1023
    int xcd = blk & 7;
    int n = xcd >> 1;
    int i64 = (blk >> 3) + (xcd & 1) * 128;     // 0..255; block covers l = i64*16 ..+16
    int tid = threadIdx.x;
    if (tid < 16) best[(size_t)n * LL + i64 * 16 + tid] = 0ull;

    int cg = tid & 15;           // channel group 0..15 (4 channels each)
    int l = i64 * 16 + (tid >> 4);
    int y = l >> 6, x = l & 63;
    const float* src = yhat + (size_t)n * (Cc * LL);

    float vals[16];
    float sumsq = 0.f;
#pragma unroll
    for (int ci = 0; ci < 4; ++ci) {
        const float* p = src + (cg * 4 + ci) * LL;
        float t0 = (y > 0 && x > 0)  ? p[l - 65] : 0.f;
        float t1 = (y > 0)           ? p[l - 64] : 0.f;
        float t2 = (y > 0 && x < 63) ? p[l - 63] : 0.f;
        float t3 = (x > 0)           ? p[l - 1]  : 0.f;
        vals[ci * 4 + 0] = t0; vals[ci * 4 + 1] = t1;
        vals[ci * 4 + 2] = t2; vals[ci * 4 + 3] = t3;
        sumsq += t0 * t0 + t1 * t1 + t2 * t2 + t3 * t3;
    }
    sumsq += __shfl_xor(sumsq, 1, 64);
    sumsq += __shfl_xor(sumsq, 2, 64);
    sumsq += __shfl_xor(sumsq, 4, 64);
    sumsq += __shfl_xor(sumsq, 8, 64);
    float inv = 1.f / fmaxf(sqrtf(sumsq), 1e-12f);

    size_t nl = (size_t)n * LL + l;
    unsigned short* dh = VhT + nl * KK + cg * 16;
    unsigned short* dl = VlT + nl * KK + cg * 16;
#pragma unroll
    for (int ci = 0; ci < 4; ++ci) {
        ushort4 hv, lv;
        unsigned short* ph = &hv.x;
        unsigned short* pl = &lv.x;
#pragma unroll
        for (int tp = 0; tp < 4; ++tp) {
            float v = vals[ci * 4 + tp] * inv;
            _Float16 h = (fabsf(v) < 6.1035e-5f) ? (_Float16)0 : (_Float16)v;
            _Float16 lo = (_Float16)((v - (float)h) * 2048.0f);
            ph[tp] = h2u(h * (_Float16)2048.0f);   // exact pow2 scale
            pl[tp] = h2u(lo);
        }
        *(ushort4*)(dh + ci * 4) = hv;
        *(ushort4*)(dl + ci * 4) = lv;
    }
}

// Kernel 2: triangular 128x128-tiled similarity-max via split-fp16 32x32x16 MFMA.
// NO LDS, NO BARRIERS: each wave loads its MFMA fragments directly from global
// (L2-resident: per-XCD working set = 4MB pinned). Lane r5 reads 16B of row
// (tile + r*32 + r5) at k-offset kc*16 + h5*8 — the exact A/B register layout.
// The 4 (kc,h5) slices of a row tile one 64B line -> no over-fetch. The compiler
// is free to pipeline global_load_dwordx4 <-> v_mfma with fine-grained vmcnt —
// the thing the 2-barrier LDS K-loop (m97 plateau, 33% MfmaUtil) forbade.
// acc = Vh1'Vh2' + Vh1'Vl2 + Vl1Vh2' = 2^22 * v1.v2 ; val = acc * 2^-22.
// 32x32x16 layouts: A/B row(col)=lane&31, k=(lane>>5)*8+j;
// C/D: col=lane&31, row=(reg&3)+8*(reg>>2)+4*(lane>>5).
__global__ __launch_bounds__(256) void simmax(const unsigned short* __restrict__ Vh,
                                              const unsigned short* __restrict__ Vl,
                                              unsigned long long* __restrict__ best) {
    int bx = blockIdx.x;              // 0..2111
    int xcd = bx & 7, idx = bx >> 3;  // XCD-pin: each XCD owns half of one batch
    int n = xcd >> 1;
    int t = (xcd & 1) * 264 + idx;    // 0..527
    int j = (int)((sqrtf(8.f * (float)t + 1.f) - 1.f) * 0.5f);
    while ((j + 1) * (j + 2) / 2 <= t) ++j;
    while (j * (j + 1) / 2 > t) --j;
    int i = t - j * (j + 1) / 2;
    int l0 = i * 128, m0 = j * 128;

    int tid = threadIdx.x;
    int w = tid >> 6, lane = tid & 63;
    int r5 = lane & 31, h5 = lane >> 5;
    int rw = (w & 1) * 64;    // wave rows (l)
    int cw = (w >> 1) * 64;   // wave cols (m)
    if ((i == j) && (rw == 64) && (cw == 0)) return;  // fully l>m: nothing to do

    const unsigned short* VhB = Vh + (size_t)n * (LL * KK);
    const unsigned short* VlB = Vl + (size_t)n * (LL * KK);

    // per-lane row base pointers (halves), k-offset h5*8 folded in
    const unsigned short* pah[2], *pal[2], *pbh[2], *pbl[2];
#pragma unroll
    for (int r = 0; r < 2; ++r) {
        size_t ar = (size_t)(l0 + rw + r * 32 + r5) * KK + h5 * 8;
        size_t br = (size_t)(m0 + cw + r * 32 + r5) * KK + h5 * 8;
        pah[r] = VhB + ar; pal[r] = VlB + ar;
        pbh[r] = VhB + br; pbl[r] = VlB + br;
    }

    f32x16 acc[2][2];
#pragma unroll
    for (int r = 0; r < 2; ++r)
#pragma unroll
        for (int c = 0; c < 2; ++c) acc[r][c] = (f32x16)0.f;

#pragma unroll 2
    for (int k0 = 0; k0 < KK; k0 += 32) {
        half8 fah[2][2], fal[2][2], fbh[2][2], fbl[2][2];
#pragma unroll
        for (int r = 0; r < 2; ++r)
#pragma unroll
            for (int kc = 0; kc < 2; ++kc) {
                int off = k0 + kc * 16;
                fah[r][kc] = *(const half8*)(pah[r] + off);
                fal[r][kc] = *(const half8*)(pal[r] + off);
                fbh[r][kc] = *(const half8*)(pbh[r] + off);
                fbl[r][kc] = *(const half8*)(pbl[r] + off);
            }
#pragma unroll
        for (int kc = 0; kc < 2; ++kc)
#pragma unroll
            for (int r = 0; r < 2; ++r)
#pragma unroll
                for (int c = 0; c < 2; ++c)
                    acc[r][c] = __builtin_amdgcn_mfma_f32_32x32x16_f16(fal[r][kc], fbh[c][kc], acc[r][c], 0, 0, 0);
#pragma unroll
        for (int kc = 0; kc < 2; ++kc)
#pragma unroll
            for (int r = 0; r < 2; ++r)
#pragma unroll
                for (int c = 0; c < 2; ++c)
                    acc[r][c] = __builtin_amdgcn_mfma_f32_32x32x16_f16(fah[r][kc], fbl[c][kc], acc[r][c], 0, 0, 0);
#pragma unroll
        for (int kc = 0; kc < 2; ++kc)
#pragma unroll
            for (int r = 0; r < 2; ++r)
#pragma unroll
                for (int c = 0; c < 2; ++c)
                    acc[r][c] = __builtin_amdgcn_mfma_f32_32x32x16_f16(fah[r][kc], fbh[c][kc], acc[r][c], 0, 0, 0);
    }

    unsigned long long* bb = best + (size_t)n * LL;
    const float s = 1.f / 4194304.f;   // 2^-22
#pragma unroll
    for (int c = 0; c < 2; ++c) {
        int m = m0 + cw + c * 32 + r5;
        unsigned long long key = 0ull;
#pragma unroll
        for (int r = 0; r < 2; ++r)
#pragma unroll
            for (int g = 0; g < 16; ++g) {
                int l = l0 + rw + r * 32 + (g & 3) + 8 * (g >> 2) + 4 * h5;
                if (l < m) {
                    float v = acc[r][c][g] * s;
                    unsigned long long k2 =
                        ((unsigned long long)f2ord(v) << 32) |
                        (unsigned long long)(0xFFFFFFFFu - (unsigned)l);
                    key = (k2 > key) ? k2 : key;
                }
            }
        unsigned long long o = __shfl_xor(key, 32, 64);
        key = (o > key) ? o : key;
        if (h5 == 0 && key != 0ull) atomicMax(bb + m, key);
    }
}

// Kernel 3: unpack best, write S, U, ref_unfold, arg (float values), m==0 overrides.
// 4096 blocks (16 channel-groups of 4) for TLP; XCD-pinned per batch.
__global__ __launch_bounds__(256) void writeout(const float* __restrict__ yhat,
                                                const float* __restrict__ yprob,
                                                const unsigned long long* __restrict__ best,
                                                float* __restrict__ out) {
    int blk = blockIdx.x;                     // 0..4095
    int xcd = blk & 7;
    int n = xcd >> 1;
    int idx = (blk >> 3) + (xcd & 1) * 512;   // 0..1023
    int mb = idx >> 4;                        // 0..63
    int fc = idx & 15;                        // channel group of 4
    int tid = threadIdx.x;
    int mm = tid & 63;
    int fs = tid >> 6;                        // 0..3
    int c = fc * 4 + fs;
    int m = mb * 64 + mm;

    unsigned long long key = best[(size_t)n * LL + m];
    unsigned l = 0xFFFFFFFFu - (unsigned)(key & 0xFFFFFFFFull);
    float val = ord2f((unsigned)(key >> 32));
    bool zero = (m == 0);
    if (zero) l = 0;
    int ly = (int)(l >> 6), lx = (int)(l & 63);

    float* Sout = out;                       // [4,1,64,64]
    float* Uout = out + 16384;               // [4,1,64,64]
    float* Rout = out + 32768;               // [4,576,4096]
    float* Aout = out + 9469952;             // [4,4096] as float values

    if (fc == 0 && fs == 0) {
        float S = zero ? 1e-8f : fminf(fmaxf(val, 1e-8f), 1.0f);
        float U = zero ? 1e-8f : fminf(fmaxf(yprob[(size_t)n * LL + l], 1e-8f), 1.0f);
        Sout[(size_t)n * LL + m] = S;
        Uout[(size_t)n * LL + m] = U;
        Aout[(size_t)n * LL + m] = zero ? -1.0f : (float)l;
    }

    const float* src = yhat + (size_t)n * (Cc * LL);
    const float* plane = src + (size_t)c * LL;
    float* dst = Rout + (size_t)n * (576 * LL) + m;
    bool fast = (!zero) && (lx >= 1) && (lx <= 61);
#pragma unroll
    for (int r3 = 0; r3 < 3; ++r3) {
        int yy = ly + r3 - 1;
        bool rowok = (!zero) && (yy >= 0) && (yy < 64);
        float t0 = 0.f, t1 = 0.f, t2 = 0.f;
        if (rowok) {
            if (fast) {
                f4a v = *(const f4a*)(plane + yy * 64 + lx - 1);
                t0 = v.x; t1 = v.y; t2 = v.z;
            } else {
                if (lx > 0)  t0 = plane[yy * 64 + lx - 1];
                t1 = plane[yy * 64 + lx];
                if (lx < 63) t2 = plane[yy * 64 + lx + 1];
            }
        }
        size_t f = (size_t)(c * 9 + r3 * 3) * LL;
        __builtin_nontemporal_store(t0, dst + f);
        __builtin_nontemporal_store(t1, dst + f + LL);
        __builtin_nontemporal_store(t2, dst + f + 2 * (size_t)LL);
    }
}

extern "C" void kernel_launch(void* const* d_in, const int* in_sizes, int n_in,
                              void* d_out, int out_size, void* d_ws, size_t ws_size,
                              hipStream_t stream) {
    const float* yhat  = (const float*)d_in[0];
    const float* yprob = (const float*)d_in[1];
    float* out = (float*)d_out;

    unsigned short* VhT = (unsigned short*)d_ws;                       // 8 MiB
    unsigned short* VlT = (unsigned short*)((char*)d_ws + 8388608);    // 8 MiB
    unsigned long long* best =
        (unsigned long long*)((char*)d_ws + 16777216);                 // 128 KiB

    build_v<<<1024, 256, 0, stream>>>(yhat, VhT, VlT, best);
    simmax<<<Nn * TRI2, 256, 0, stream>>>(VhT, VlT, best);
    writeout<<<4096, 256, 0, stream>>>(yhat, yprob, best, out);
}

// Round 10
// 157.826 us; speedup vs baseline: 1.4274x; 1.4274x over previous
//
#include <hip/hip_runtime.h>
#include <stdint.h>

#define Nn 4
#define Cc 64
#define LL 4096   // H*W
#define KK 256    // feature dim: 64 channels * 4 causal taps
#define TRI2 528  // 32*33/2 triangular 128x128 tile pairs per batch

typedef _Float16 half8 __attribute__((ext_vector_type(8)));
typedef float f32x16 __attribute__((ext_vector_type(16)));
typedef float f4a __attribute__((ext_vector_type(4), aligned(4)));

__device__ __forceinline__ unsigned f2ord(float f) {
    unsigned u = __float_as_uint(f);
    return u ^ ((u & 0x80000000u) ? 0xFFFFFFFFu : 0x80000000u);
}
__device__ __forceinline__ float ord2f(unsigned o) {
    unsigned u = (o & 0x80000000u) ? (o ^ 0x80000000u) : ~o;
    return __uint_as_float(u);
}
__device__ __forceinline__ unsigned short h2u(_Float16 h) {
    union { _Float16 f; unsigned short u; } x; x.f = h; return x.u;
}

// Kernel 1: normalized masked context vectors, split fp16 hi/lo, pre-scaled
//   Vh' = 2048*fp16(v), Vl = fp16((v - fp16(v)) * 2048),
// written in FRAGMENT-MAJOR layout: for batch n, element (l,k) lives at
//   ((l>>5)*16 + (k>>4))*64 + (l&31) + 32*((k>>3)&1), times 8 halves + (k&7).
// This is exactly the 32x32x16 MFMA A/B register image, so simmax wave loads
// are 1KB-contiguous. Thread (l, cg) owns k16=cg (16 halves). XCD-pinned;
// zeroes its slice of `best`.
__global__ __launch_bounds__(256) void build_v(const float* __restrict__ yhat,
                                               unsigned short* __restrict__ VhT,
                                               unsigned short* __restrict__ VlT,
                                               unsigned long long* __restrict__ best) {
    int blk = blockIdx.x;                       // 0..1023
    int xcd = blk & 7;
    int n = xcd >> 1;
    int i64 = (blk >> 3) + (xcd & 1) * 128;     // 0..255; block covers l = i64*16 ..+16
    int tid = threadIdx.x;
    if (tid < 16) best[(size_t)n * LL + i64 * 16 + tid] = 0ull;

    int cg = tid & 15;           // k16 chunk owner (channels cg*4 .. cg*4+3)
    int l = i64 * 16 + (tid >> 4);
    int y = l >> 6, x = l & 63;
    const float* src = yhat + (size_t)n * (Cc * LL);

    float vals[16];
    float sumsq = 0.f;
#pragma unroll
    for (int ci = 0; ci < 4; ++ci) {
        const float* p = src + (cg * 4 + ci) * LL;
        float t0 = (y > 0 && x > 0)  ? p[l - 65] : 0.f;
        float t1 = (y > 0)           ? p[l - 64] : 0.f;
        float t2 = (y > 0 && x < 63) ? p[l - 63] : 0.f;
        float t3 = (x > 0)           ? p[l - 1]  : 0.f;
        vals[ci * 4 + 0] = t0; vals[ci * 4 + 1] = t1;
        vals[ci * 4 + 2] = t2; vals[ci * 4 + 3] = t3;
        sumsq += t0 * t0 + t1 * t1 + t2 * t2 + t3 * t3;
    }
    sumsq += __shfl_xor(sumsq, 1, 64);
    sumsq += __shfl_xor(sumsq, 2, 64);
    sumsq += __shfl_xor(sumsq, 4, 64);
    sumsq += __shfl_xor(sumsq, 8, 64);
    float inv = 1.f / fmaxf(sqrtf(sumsq), 1e-12f);

    __align__(16) unsigned short hs[16];
    __align__(16) unsigned short ls[16];
#pragma unroll
    for (int kl = 0; kl < 16; ++kl) {
        float v = vals[kl] * inv;
        _Float16 h = (fabsf(v) < 6.1035e-5f) ? (_Float16)0 : (_Float16)v;
        _Float16 lo = (_Float16)((v - (float)h) * 2048.0f);
        hs[kl] = h2u(h * (_Float16)2048.0f);   // exact pow2 scale
        ls[kl] = h2u(lo);
    }

    unsigned short* dhb = VhT + (size_t)n * (LL * KK);
    unsigned short* dlb = VlT + (size_t)n * (LL * KK);
    size_t gbase = ((size_t)((l >> 5) * 16 + cg)) * 64;
    size_t a0 = (gbase + (l & 31)) * 8;        // k-half 0 (k&8 == 0)
    size_t a1 = (gbase + 32 + (l & 31)) * 8;   // k-half 1
    *(uint4*)(dhb + a0) = *(const uint4*)&hs[0];
    *(uint4*)(dhb + a1) = *(const uint4*)&hs[8];
    *(uint4*)(dlb + a0) = *(const uint4*)&ls[0];
    *(uint4*)(dlb + a1) = *(const uint4*)&ls[8];
}

// Kernel 2: triangular 128x128-tiled similarity-max, NO LDS, NO BARRIERS.
// 2 waves/block (128 thr), each wave owns 64 rows x 128 cols (acc 2x4 of 32x32).
// Fragment-major V makes every A/B fragment load one contiguous 1KB
// global_load_dwordx4 per wave (TA-friendly; R9's scattered-row failure fixed).
// Compiler freely pipelines loads <-> MFMA with fine-grained vmcnt (no barrier
// drain -> past the m97 33%-MfmaUtil plateau).
// acc = Vh1'Vh2' + Vh1'Vl2 + Vl1Vh2' = 2^22 * v1.v2 ; val = acc * 2^-22.
// C/D: col=lane&31, row=(reg&3)+8*(reg>>2)+4*(lane>>5).
__global__ __launch_bounds__(128, 2) void simmax(const unsigned short* __restrict__ Vh,
                                                 const unsigned short* __restrict__ Vl,
                                                 unsigned long long* __restrict__ best) {
    int bx = blockIdx.x;              // 0..2111
    int xcd = bx & 7, idx = bx >> 3;  // XCD-pin: each XCD owns half of one batch
    int n = xcd >> 1;
    int t = (xcd & 1) * 264 + idx;    // 0..527
    int j = (int)((sqrtf(8.f * (float)t + 1.f) - 1.f) * 0.5f);
    while ((j + 1) * (j + 2) / 2 <= t) ++j;
    while (j * (j + 1) / 2 > t) --j;
    int i = t - j * (j + 1) / 2;
    int l0 = i * 128, m0 = j * 128;

    int tid = threadIdx.x;
    int w = tid >> 6, lane = tid & 63;
    int r5 = lane & 31, h5 = lane >> 5;
    int rw = w * 64;                  // wave rows (l): 0 or 64

    const unsigned short* VhB = Vh + (size_t)n * (LL * KK);
    const unsigned short* VlB = Vl + (size_t)n * (LL * KK);

    int gA = (l0 + rw) >> 5;          // + r (2 groups)
    int gB = m0 >> 5;                 // + c (4 groups)

    f32x16 acc[2][4];
#pragma unroll
    for (int r = 0; r < 2; ++r)
#pragma unroll
        for (int c = 0; c < 4; ++c) acc[r][c] = (f32x16)0.f;

#pragma unroll 2
    for (int k16 = 0; k16 < 16; ++k16) {
        half8 ah[2], al[2], bh[4], bl[4];
#pragma unroll
        for (int r = 0; r < 2; ++r) {
            size_t off = ((size_t)((gA + r) * 16 + k16) * 64 + lane) * 8;
            ah[r] = *(const half8*)(VhB + off);
            al[r] = *(const half8*)(VlB + off);
        }
#pragma unroll
        for (int c = 0; c < 4; ++c) {
            size_t off = ((size_t)((gB + c) * 16 + k16) * 64 + lane) * 8;
            bh[c] = *(const half8*)(VhB + off);
            bl[c] = *(const half8*)(VlB + off);
        }
#pragma unroll
        for (int c = 0; c < 4; ++c)
#pragma unroll
            for (int r = 0; r < 2; ++r) {
                acc[r][c] = __builtin_amdgcn_mfma_f32_32x32x16_f16(al[r], bh[c], acc[r][c], 0, 0, 0);
                acc[r][c] = __builtin_amdgcn_mfma_f32_32x32x16_f16(ah[r], bl[c], acc[r][c], 0, 0, 0);
                acc[r][c] = __builtin_amdgcn_mfma_f32_32x32x16_f16(ah[r], bh[c], acc[r][c], 0, 0, 0);
            }
    }

    unsigned long long* bb = best + (size_t)n * LL;
    const float s = 1.f / 4194304.f;   // 2^-22
#pragma unroll
    for (int c = 0; c < 4; ++c) {
        int m = m0 + c * 32 + r5;
        unsigned long long key = 0ull;
#pragma unroll
        for (int r = 0; r < 2; ++r)
#pragma unroll
            for (int g = 0; g < 16; ++g) {
                int l = l0 + rw + r * 32 + (g & 3) + 8 * (g >> 2) + 4 * h5;
                if (l < m) {
                    float v = acc[r][c][g] * s;
                    unsigned long long k2 =
                        ((unsigned long long)f2ord(v) << 32) |
                        (unsigned long long)(0xFFFFFFFFu - (unsigned)l);
                    key = (k2 > key) ? k2 : key;
                }
            }
        unsigned long long o = __shfl_xor(key, 32, 64);
        key = (o > key) ? o : key;
        if (h5 == 0 && key != 0ull) atomicMax(bb + m, key);
    }
}

// Kernel 3: unpack best, write S, U, ref_unfold, arg (float values), m==0 overrides.
// 4096 blocks (16 channel-groups of 4) for TLP; XCD-pinned per batch.
__global__ __launch_bounds__(256) void writeout(const float* __restrict__ yhat,
                                                const float* __restrict__ yprob,
                                                const unsigned long long* __restrict__ best,
                                                float* __restrict__ out) {
    int blk = blockIdx.x;                     // 0..4095
    int xcd = blk & 7;
    int n = xcd >> 1;
    int idx = (blk >> 3) + (xcd & 1) * 512;   // 0..1023
    int mb = idx >> 4;                        // 0..63
    int fc = idx & 15;                        // channel group of 4
    int tid = threadIdx.x;
    int mm = tid & 63;
    int fs = tid >> 6;                        // 0..3
    int c = fc * 4 + fs;
    int m = mb * 64 + mm;

    unsigned long long key = best[(size_t)n * LL + m];
    unsigned l = 0xFFFFFFFFu - (unsigned)(key & 0xFFFFFFFFull);
    float val = ord2f((unsigned)(key >> 32));
    bool zero = (m == 0);
    if (zero) l = 0;
    int ly = (int)(l >> 6), lx = (int)(l & 63);

    float* Sout = out;                       // [4,1,64,64]
    float* Uout = out + 16384;               // [4,1,64,64]
    float* Rout = out + 32768;               // [4,576,4096]
    float* Aout = out + 9469952;             // [4,4096] as float values

    if (fc == 0 && fs == 0) {
        float S = zero ? 1e-8f : fminf(fmaxf(val, 1e-8f), 1.0f);
        float U = zero ? 1e-8f : fminf(fmaxf(yprob[(size_t)n * LL + l], 1e-8f), 1.0f);
        Sout[(size_t)n * LL + m] = S;
        Uout[(size_t)n * LL + m] = U;
        Aout[(size_t)n * LL + m] = zero ? -1.0f : (float)l;
    }

    const float* src = yhat + (size_t)n * (Cc * LL);
    const float* plane = src + (size_t)c * LL;
    float* dst = Rout + (size_t)n * (576 * LL) + m;
    bool fast = (!zero) && (lx >= 1) && (lx <= 61);
#pragma unroll
    for (int r3 = 0; r3 < 3; ++r3) {
        int yy = ly + r3 - 1;
        bool rowok = (!zero) && (yy >= 0) && (yy < 64);
        float t0 = 0.f, t1 = 0.f, t2 = 0.f;
        if (rowok) {
            if (fast) {
                f4a v = *(const f4a*)(plane + yy * 64 + lx - 1);
                t0 = v.x; t1 = v.y; t2 = v.z;
            } else {
                if (lx > 0)  t0 = plane[yy * 64 + lx - 1];
                t1 = plane[yy * 64 + lx];
                if (lx < 63) t2 = plane[yy * 64 + lx + 1];
            }
        }
        size_t f = (size_t)(c * 9 + r3 * 3) * LL;
        __builtin_nontemporal_store(t0, dst + f);
        __builtin_nontemporal_store(t1, dst + f + LL);
        __builtin_nontemporal_store(t2, dst + f + 2 * (size_t)LL);
    }
}

extern "C" void kernel_launch(void* const* d_in, const int* in_sizes, int n_in,
                              void* d_out, int out_size, void* d_ws, size_t ws_size,
                              hipStream_t stream) {
    const float* yhat  = (const float*)d_in[0];
    const float* yprob = (const float*)d_in[1];
    float* out = (float*)d_out;

    unsigned short* VhT = (unsigned short*)d_ws;                       // 8 MiB (fragment-major)
    unsigned short* VlT = (unsigned short*)((char*)d_ws + 8388608);    // 8 MiB (fragment-major)
    unsigned long long* best =
        (unsigned long long*)((char*)d_ws + 16777216);                 // 128 KiB

    build_v<<<1024, 256, 0, stream>>>(yhat, VhT, VlT, best);
    simmax<<<Nn * TRI2, 128, 0, stream>>>(VhT, VlT, best);
    writeout<<<4096, 256, 0, stream>>>(yhat, yprob, best, out);
}